// Round 1
// baseline (1482.740 us; speedup 1.0000x reference)
//
#include <hip/hip_runtime.h>

typedef __bf16 bf16x8 __attribute__((ext_vector_type(8)));
typedef short  s16x8  __attribute__((ext_vector_type(8)));
typedef float  f32x4  __attribute__((ext_vector_type(4)));

#define DEVINL __device__ __forceinline__

DEVINL unsigned short f2bf(float f) {
  unsigned int u = __builtin_bit_cast(unsigned int, f);
  u += 0x7fffu + ((u >> 16) & 1u);   // round-to-nearest-even
  return (unsigned short)(u >> 16);
}

DEVINL void async16(const void* g, void* l) {
  __builtin_amdgcn_global_load_lds(
      (const __attribute__((address_space(1))) unsigned int*)g,
      (__attribute__((address_space(3))) unsigned int*)l, 16, 0, 0);
}

// ---------------- conversion kernels ----------------

__global__ void cvt_f32_bf16(const float* __restrict__ in,
                             unsigned short* __restrict__ out, int n4) {
  int i = blockIdx.x * blockDim.x + threadIdx.x;
  int stride = gridDim.x * blockDim.x;
  for (; i < n4; i += stride) {
    float4 v = ((const float4*)in)[i];
    ushort4 o;
    o.x = f2bf(v.x); o.y = f2bf(v.y); o.z = f2bf(v.z); o.w = f2bf(v.w);
    ((ushort4*)out)[i] = o;
  }
}

// in: [R][C] fp32  ->  out: [C][R] bf16
__global__ void transpose_cvt(const float* __restrict__ in,
                              unsigned short* __restrict__ out, int R, int C) {
  __shared__ unsigned short tile[32][33];
  int bc = blockIdx.x * 32, br = blockIdx.y * 32;
  int tx = threadIdx.x & 31, ty = threadIdx.x >> 5;   // 256 threads: ty 0..7
#pragma unroll
  for (int i = 0; i < 32; i += 8)
    tile[ty + i][tx] = f2bf(in[(size_t)(br + ty + i) * C + (bc + tx)]);
  __syncthreads();
#pragma unroll
  for (int i = 0; i < 32; i += 8)
    out[(size_t)(bc + ty + i) * R + (br + tx)] = tile[tx][ty + i];
}

__global__ void qconst(const float* __restrict__ theta,
                       const float* __restrict__ wre,
                       const float* __restrict__ wim,
                       float* __restrict__ c1, int n) {
  int i = blockIdx.x * blockDim.x + threadIdx.x;
  if (i < n) {
    float t = theta[i];
    c1[i] = (cosf(t) * wre[i] + sinf(t) * wim[i]) * wim[i] * 0.1f;
  }
}

// ---------------- GEMM: C = A[M][K] * Bt[N][K]^T, 128x128 tile ----------------
// FUSED: C = relu(h + c1[n]*sin(theta[n]+0.1h)), h = acc+bias[n], store bf16
// else : C = acc + bias[n], store fp32

template <int KSTEPS, bool FUSED>
__global__ __launch_bounds__(256) void gemm_bt(
    const unsigned short* __restrict__ A,
    const unsigned short* __restrict__ Bt,
    const float* __restrict__ bias,
    const float* __restrict__ theta,
    const float* __restrict__ c1,
    void* __restrict__ Cout,
    int N, int nTilesN) {
  constexpr int K = KSTEPS * 32;
  __shared__ __align__(16) short lds[2][2][128 * 32];

  // bijective XCD swizzle (grid % 8 == 0 for both GEMMs here)
  int nwg = gridDim.x;
  int per = nwg >> 3;
  int wg = blockIdx.x;
  int sw = (wg & 7) * per + (wg >> 3);
  int tm = sw / nTilesN, tn = sw % nTilesN;
  int rowBase = tm * 128, colBase = tn * 128;

  const int t = threadIdx.x;
  const int lane = t & 63;
  const int wid = t >> 6;
  const int wr = wid >> 1, wc = wid & 1;
  const int lr = lane & 15;
  const int lk = (lane >> 4) * 8;

  f32x4 acc[4][4] = {};

  auto stage = [&](int buf, int kt) {
    int k0 = kt * 32;
#pragma unroll
    for (int i = 0; i < 2; ++i) {
      int off = i * 4096 + t * 16;          // byte offset in 8 KiB tile
      int row = off >> 6;                   // 64 B per row (32 bf16)
      int col = (off & 63) >> 1;            // element col
      async16(A + (size_t)(rowBase + row) * K + k0 + col,
              (char*)&lds[buf][0][0] + off);
    }
#pragma unroll
    for (int i = 0; i < 2; ++i) {
      int off = i * 4096 + t * 16;
      int row = off >> 6;
      int col = (off & 63) >> 1;
      async16(Bt + (size_t)(colBase + row) * K + k0 + col,
              (char*)&lds[buf][1][0] + off);
    }
  };

  stage(0, 0);
  __syncthreads();
  int cur = 0;
  for (int kt = 0; kt < KSTEPS; ++kt) {
    if (kt + 1 < KSTEPS) stage(cur ^ 1, kt + 1);
    const short* As = &lds[cur][0][0];
    const short* Bs = &lds[cur][1][0];
    bf16x8 af[4], bfr[4];
#pragma unroll
    for (int mi = 0; mi < 4; ++mi)
      af[mi] = __builtin_bit_cast(
          bf16x8, *(const s16x8*)&As[(wr * 64 + mi * 16 + lr) * 32 + lk]);
#pragma unroll
    for (int ni = 0; ni < 4; ++ni)
      bfr[ni] = __builtin_bit_cast(
          bf16x8, *(const s16x8*)&Bs[(wc * 64 + ni * 16 + lr) * 32 + lk]);
#pragma unroll
    for (int mi = 0; mi < 4; ++mi)
#pragma unroll
      for (int ni = 0; ni < 4; ++ni)
        acc[mi][ni] = __builtin_amdgcn_mfma_f32_16x16x32_bf16(
            af[mi], bfr[ni], acc[mi][ni], 0, 0, 0);
    __syncthreads();
    cur ^= 1;
  }

  // epilogue
  int baseM = rowBase + wr * 64;
  int baseN = colBase + wc * 64;
  int rowOff = (lane >> 4) * 4;
#pragma unroll
  for (int ni = 0; ni < 4; ++ni) {
    int n = baseN + ni * 16 + lr;
    float bv = bias[n];
    float th = 0.f, cc = 0.f;
    if (FUSED) { th = theta[n]; cc = c1[n]; }
#pragma unroll
    for (int mi = 0; mi < 4; ++mi) {
#pragma unroll
      for (int r = 0; r < 4; ++r) {
        size_t m = (size_t)(baseM + mi * 16 + rowOff + r);
        float h = acc[mi][ni][r] + bv;
        if (FUSED) {
          float q = h + cc * sinf(th + 0.1f * h);
          q = fmaxf(q, 0.f);
          ((unsigned short*)Cout)[m * N + n] = f2bf(q);
        } else {
          ((float*)Cout)[m * N + n] = h;
        }
      }
    }
  }
}

// ---------------- launch ----------------

extern "C" void kernel_launch(void* const* d_in, const int* in_sizes, int n_in,
                              void* d_out, int out_size, void* d_ws,
                              size_t ws_size, hipStream_t stream) {
  const float* x     = (const float*)d_in[0];
  const float* W1    = (const float*)d_in[1];
  const float* b1    = (const float*)d_in[2];
  const float* theta = (const float*)d_in[3];
  const float* qwr   = (const float*)d_in[4];
  const float* qwi   = (const float*)d_in[5];
  const float* W2    = (const float*)d_in[6];
  const float* b2    = (const float*)d_in[7];
  float* out = (float*)d_out;

  const int M = 4 * 2048;            // 8192
  const int DM = 1024, DF = 4096;

  size_t need = ((size_t)96 << 20) + DF * sizeof(float);
  if (ws_size < need) return;        // avoid corrupting memory if ws too small

  char* ws = (char*)d_ws;
  unsigned short* xb   = (unsigned short*)ws;                          // 16 MiB
  unsigned short* w1t  = (unsigned short*)(ws + ((size_t)16 << 20));   //  8 MiB
  unsigned short* w2t  = (unsigned short*)(ws + ((size_t)24 << 20));   //  8 MiB
  unsigned short* actb = (unsigned short*)(ws + ((size_t)32 << 20));   // 64 MiB
  float* c1 = (float*)(ws + ((size_t)96 << 20));

  cvt_f32_bf16<<<2048, 256, 0, stream>>>(x, xb, M * DM / 4);
  transpose_cvt<<<dim3(DF / 32, DM / 32), 256, 0, stream>>>(W1, w1t, DM, DF);
  transpose_cvt<<<dim3(DM / 32, DF / 32), 256, 0, stream>>>(W2, w2t, DF, DM);
  qconst<<<DF / 256, 256, 0, stream>>>(theta, qwr, qwi, c1, DF);

  gemm_bt<1024 / 32, true><<<(M / 128) * (DF / 128), 256, 0, stream>>>(
      xb, w1t, b1, theta, c1, (void*)actb, DF, DF / 128);
  gemm_bt<4096 / 32, false><<<(M / 128) * (DM / 128), 256, 0, stream>>>(
      actb, w2t, b2, nullptr, nullptr, (void*)out, DM, DM / 128);
}

// Round 2
// 199.384 us; speedup vs baseline: 7.4366x; 7.4366x over previous
//
#include <hip/hip_runtime.h>

typedef __bf16 bf16x8 __attribute__((ext_vector_type(8)));
typedef short  s16x8  __attribute__((ext_vector_type(8)));
typedef float  f32x4  __attribute__((ext_vector_type(4)));

#define DEVINL __device__ __forceinline__

DEVINL unsigned short f2bf(float f) {
  unsigned int u = __builtin_bit_cast(unsigned int, f);
  u += 0x7fffu + ((u >> 16) & 1u);   // round-to-nearest-even
  return (unsigned short)(u >> 16);
}

DEVINL void async16(const void* g, void* l) {
  __builtin_amdgcn_global_load_lds(
      (const __attribute__((address_space(1))) unsigned int*)g,
      (__attribute__((address_space(3))) unsigned int*)l, 16, 0, 0);
}

// ---------------- conversion kernels ----------------

__global__ void cvt_f32_bf16(const float* __restrict__ in,
                             unsigned short* __restrict__ out, int n4) {
  int i = blockIdx.x * blockDim.x + threadIdx.x;
  int stride = gridDim.x * blockDim.x;
  for (; i < n4; i += stride) {
    float4 v = ((const float4*)in)[i];
    ushort4 o;
    o.x = f2bf(v.x); o.y = f2bf(v.y); o.z = f2bf(v.z); o.w = f2bf(v.w);
    ((ushort4*)out)[i] = o;
  }
}

// in: [R][C] fp32  ->  out: [C][R] bf16
__global__ void transpose_cvt(const float* __restrict__ in,
                              unsigned short* __restrict__ out, int R, int C) {
  __shared__ unsigned short tile[32][33];
  int bc = blockIdx.x * 32, br = blockIdx.y * 32;
  int tx = threadIdx.x & 31, ty = threadIdx.x >> 5;   // 256 threads: ty 0..7
#pragma unroll
  for (int i = 0; i < 32; i += 8)
    tile[ty + i][tx] = f2bf(in[(size_t)(br + ty + i) * C + (bc + tx)]);
  __syncthreads();
#pragma unroll
  for (int i = 0; i < 32; i += 8)
    out[(size_t)(bc + ty + i) * R + (br + tx)] = tile[tx][ty + i];
}

__global__ void qconst(const float* __restrict__ theta,
                       const float* __restrict__ wre,
                       const float* __restrict__ wim,
                       float* __restrict__ c1, int n) {
  int i = blockIdx.x * blockDim.x + threadIdx.x;
  if (i < n) {
    float t = theta[i];
    c1[i] = (cosf(t) * wre[i] + sinf(t) * wim[i]) * wim[i] * 0.1f;
  }
}

// ---------------- GEMM: C = A[M][K] * Bt[N][K]^T, 128x128 tile ----------------
// FUSED: C = relu(h + c1[n]*sin(theta[n]+0.1h)), h = acc+bias[n], store bf16
// else : C = acc + bias[n], store fp32
// m97 structure: compile-time double-buffer indices (no runtime lds[cur]),
// global_load_lds width-16 staging, 4 waves x (64x64) acc, 16x16x32 bf16 MFMA.

template <int KSTEPS, bool FUSED>
__global__ __launch_bounds__(256) void gemm_bt(
    const unsigned short* __restrict__ A,
    const unsigned short* __restrict__ Bt,
    const float* __restrict__ bias,
    const float* __restrict__ theta,
    const float* __restrict__ c1,
    void* __restrict__ Cout,
    int N, int nTilesN) {
  constexpr int K = KSTEPS * 32;
  __shared__ __align__(16) short lds[2][2][128 * 32];

  // bijective XCD swizzle (grid % 8 == 0 for both GEMMs here)
  int nwg = gridDim.x;
  int per = nwg >> 3;
  int wg = blockIdx.x;
  int sw = (wg & 7) * per + (wg >> 3);
  int tm = sw / nTilesN, tn = sw % nTilesN;
  int rowBase = tm * 128, colBase = tn * 128;

  const int t = threadIdx.x;
  const int lane = t & 63;
  const int wid = t >> 6;
  const int wr = wid >> 1, wc = wid & 1;
  const int lr = lane & 15;
  const int lk = (lane >> 4) * 8;

  // hoisted per-thread staging addresses (16B per thread, wave-contiguous LDS)
  const int off0 = t * 16;               // byte offset within half-tile
  const int srow = off0 >> 6;            // 64 B per LDS row (32 bf16)
  const int scol = (off0 & 63) >> 1;     // element col: 0,8,16,24
  const unsigned short* Arow0 = A  + (size_t)(rowBase + srow) * K + scol;
  const unsigned short* Arow1 = A  + (size_t)(rowBase + 64 + srow) * K + scol;
  const unsigned short* Brow0 = Bt + (size_t)(colBase + srow) * K + scol;
  const unsigned short* Brow1 = Bt + (size_t)(colBase + 64 + srow) * K + scol;

#define STAGE(BUF, KT) do {                                          \
    int k0_ = (KT) * 32;                                             \
    async16(Arow0 + k0_, (char*)&lds[BUF][0][0] + off0);             \
    async16(Arow1 + k0_, (char*)&lds[BUF][0][0] + 4096 + off0);      \
    async16(Brow0 + k0_, (char*)&lds[BUF][1][0] + off0);             \
    async16(Brow1 + k0_, (char*)&lds[BUF][1][0] + 4096 + off0);      \
  } while (0)

  f32x4 acc[4][4] = {};

#define COMPUTE(BUF) do {                                            \
    const short* As_ = &lds[BUF][0][0];                              \
    const short* Bs_ = &lds[BUF][1][0];                              \
    bf16x8 af_[4], bf_[4];                                           \
    _Pragma("unroll")                                                \
    for (int mi = 0; mi < 4; ++mi)                                   \
      af_[mi] = __builtin_bit_cast(                                  \
          bf16x8, *(const s16x8*)&As_[(wr * 64 + mi * 16 + lr) * 32 + lk]); \
    _Pragma("unroll")                                                \
    for (int ni = 0; ni < 4; ++ni)                                   \
      bf_[ni] = __builtin_bit_cast(                                  \
          bf16x8, *(const s16x8*)&Bs_[(wc * 64 + ni * 16 + lr) * 32 + lk]); \
    _Pragma("unroll")                                                \
    for (int mi = 0; mi < 4; ++mi)                                   \
      _Pragma("unroll")                                              \
      for (int ni = 0; ni < 4; ++ni)                                 \
        acc[mi][ni] = __builtin_amdgcn_mfma_f32_16x16x32_bf16(       \
            af_[mi], bf_[ni], acc[mi][ni], 0, 0, 0);                 \
  } while (0)

  STAGE(0, 0);
  __syncthreads();
  // KSTEPS is even for both instantiations (32, 128)
  for (int kt = 0; kt < KSTEPS; kt += 2) {
    STAGE(1, kt + 1);                    // prefetch into buf1 (no hazard w/ buf0 reads)
    COMPUTE(0);
    __syncthreads();                     // drains vmcnt -> buf1 ready
    if (kt + 2 < KSTEPS) STAGE(0, kt + 2);
    COMPUTE(1);
    __syncthreads();
  }
#undef STAGE
#undef COMPUTE

  // epilogue
  int baseM = rowBase + wr * 64;
  int baseN = colBase + wc * 64;
  int rowOff = (lane >> 4) * 4;
#pragma unroll
  for (int ni = 0; ni < 4; ++ni) {
    int n = baseN + ni * 16 + lr;
    float bv = bias[n];
    float th = 0.f, cc = 0.f;
    if (FUSED) { th = theta[n]; cc = c1[n]; }
#pragma unroll
    for (int mi = 0; mi < 4; ++mi) {
#pragma unroll
      for (int r = 0; r < 4; ++r) {
        size_t m = (size_t)(baseM + mi * 16 + rowOff + r);
        float h = acc[mi][ni][r] + bv;
        if (FUSED) {
          float q = h + cc * __sinf(th + 0.1f * h);
          q = fmaxf(q, 0.f);
          ((unsigned short*)Cout)[m * N + n] = f2bf(q);
        } else {
          ((float*)Cout)[m * N + n] = h;
        }
      }
    }
  }
}

// ---------------- launch ----------------

extern "C" void kernel_launch(void* const* d_in, const int* in_sizes, int n_in,
                              void* d_out, int out_size, void* d_ws,
                              size_t ws_size, hipStream_t stream) {
  const float* x     = (const float*)d_in[0];
  const float* W1    = (const float*)d_in[1];
  const float* b1    = (const float*)d_in[2];
  const float* theta = (const float*)d_in[3];
  const float* qwr   = (const float*)d_in[4];
  const float* qwi   = (const float*)d_in[5];
  const float* W2    = (const float*)d_in[6];
  const float* b2    = (const float*)d_in[7];
  float* out = (float*)d_out;

  const int M = 4 * 2048;            // 8192
  const int DM = 1024, DF = 4096;

  size_t need = ((size_t)96 << 20) + DF * sizeof(float);
  if (ws_size < need) return;        // avoid corrupting memory if ws too small

  char* ws = (char*)d_ws;
  unsigned short* xb   = (unsigned short*)ws;                          // 16 MiB
  unsigned short* w1t  = (unsigned short*)(ws + ((size_t)16 << 20));   //  8 MiB
  unsigned short* w2t  = (unsigned short*)(ws + ((size_t)24 << 20));   //  8 MiB
  unsigned short* actb = (unsigned short*)(ws + ((size_t)32 << 20));   // 64 MiB
  float* c1 = (float*)(ws + ((size_t)96 << 20));

  cvt_f32_bf16<<<2048, 256, 0, stream>>>(x, xb, M * DM / 4);
  transpose_cvt<<<dim3(DF / 32, DM / 32), 256, 0, stream>>>(W1, w1t, DM, DF);
  transpose_cvt<<<dim3(DM / 32, DF / 32), 256, 0, stream>>>(W2, w2t, DF, DM);
  qconst<<<DF / 256, 256, 0, stream>>>(theta, qwr, qwi, c1, DF);

  gemm_bt<1024 / 32, true><<<(M / 128) * (DF / 128), 256, 0, stream>>>(
      xb, w1t, b1, theta, c1, (void*)actb, DF, DF / 128);
  gemm_bt<4096 / 32, false><<<(M / 128) * (DM / 128), 256, 0, stream>>>(
      actb, w2t, b2, nullptr, nullptr, (void*)out, DM, DM / 128);
}

// Round 3
// 165.404 us; speedup vs baseline: 8.9643x; 1.2054x over previous
//
#include <hip/hip_runtime.h>

typedef __bf16 bf16x8 __attribute__((ext_vector_type(8)));
typedef short  s16x8  __attribute__((ext_vector_type(8)));
typedef float  f32x4  __attribute__((ext_vector_type(4)));

#define DEVINL __device__ __forceinline__

DEVINL unsigned short f2bf(float f) {
  unsigned int u = __builtin_bit_cast(unsigned int, f);
  u += 0x7fffu + ((u >> 16) & 1u);   // round-to-nearest-even
  return (unsigned short)(u >> 16);
}

DEVINL void async16(const void* g, void* l) {
  __builtin_amdgcn_global_load_lds(
      (const __attribute__((address_space(1))) unsigned int*)g,
      (__attribute__((address_space(3))) unsigned int*)l, 16, 0, 0);
}

// ---------------- conversion kernels ----------------

__global__ void cvt_f32_bf16(const float* __restrict__ in,
                             unsigned short* __restrict__ out, int n4) {
  int i = blockIdx.x * blockDim.x + threadIdx.x;
  int stride = gridDim.x * blockDim.x;
  for (; i < n4; i += stride) {
    float4 v = ((const float4*)in)[i];
    ushort4 o;
    o.x = f2bf(v.x); o.y = f2bf(v.y); o.z = f2bf(v.z); o.w = f2bf(v.w);
    ((ushort4*)out)[i] = o;
  }
}

// in: [R][C] fp32  ->  out: [C][R] bf16
__global__ void transpose_cvt(const float* __restrict__ in,
                              unsigned short* __restrict__ out, int R, int C) {
  __shared__ unsigned short tile[32][33];
  int bc = blockIdx.x * 32, br = blockIdx.y * 32;
  int tx = threadIdx.x & 31, ty = threadIdx.x >> 5;
#pragma unroll
  for (int i = 0; i < 32; i += 8)
    tile[ty + i][tx] = f2bf(in[(size_t)(br + ty + i) * C + (bc + tx)]);
  __syncthreads();
#pragma unroll
  for (int i = 0; i < 32; i += 8)
    out[(size_t)(bc + ty + i) * R + (br + tx)] = tile[tx][ty + i];
}

__global__ void qconst(const float* __restrict__ theta,
                       const float* __restrict__ wre,
                       const float* __restrict__ wim,
                       float* __restrict__ c1, int n) {
  int i = blockIdx.x * blockDim.x + threadIdx.x;
  if (i < n) {
    float t = theta[i];
    c1[i] = (cosf(t) * wre[i] + sinf(t) * wim[i]) * wim[i] * 0.1f;
  }
}

// ---------------- 8-phase GEMM: C = A[M][K] * Bt[N][K]^T ----------------
// BMxBN tile, BK=64, 8 waves (2M x 4N), double-buffered LDS, counted vmcnt,
// XOR-swizzled LDS (pre-swizzled global source + swizzled ds_read).
// Staging schedule (group = 4 phases consuming K-tile T, buf = T&1):
//   P1/P2: issue A-loads of tile T+1 -> buf^1  (safe: that buf's A-reads
//          finished in prev group's P3, barrier-separated)
//   P3/P4: issue B-loads of tile T+2 -> buf    (safe: this tile's B-reads
//          finished by P2's closing barrier)
//   P4:    vmcnt(4) after MFMA = allow only P3/P4's B-loads outstanding
//          -> tile T+1 (A from P1/P2, B from prev group) fully arrived.
// Swizzle swz(x) = x ^ (((x>>7)&7)<<4) within a tile region (128B rows,
// 8 x 16B slots): involution; ds_read_b128 frag reads hit all 32 banks.

template <int BM, int BN, int NT, bool FUSED>
__global__ __launch_bounds__(512, 2) void gemm8p(
    const unsigned short* __restrict__ A,
    const unsigned short* __restrict__ Bt,
    const float* __restrict__ bias,
    const float* __restrict__ theta,
    const float* __restrict__ c1,
    void* __restrict__ Cout,
    int N, int nTilesN) {
  constexpr int K      = NT * 64;
  constexpr int WROWS  = BM / 2;        // per-wave output rows
  constexpr int M_REP  = WROWS / 16;    // 8 (BM=256) or 4 (BM=128)
  constexpr int MH     = M_REP / 2;
  constexpr int ABYTES = BM * 128;      // A region bytes per buffer
  constexpr int BUF    = (BM + BN) * 128;
  constexpr int LA     = ABYTES / 8192; // per-wave A loads per K-tile (4 or 2)
  constexpr int LB     = BN * 128 / 8192;
  static_assert(LB == 4 && (LA == 4 || LA == 2), "geometry");

  __shared__ __align__(16) char lds[2 * BUF];

  // bijective XCD swizzle (grid % 8 == 0 for both instantiations)
  int nwg = gridDim.x;
  int wg = blockIdx.x;
  int sw = (wg & 7) * (nwg >> 3) + (wg >> 3);
  int rowBase = (sw / nTilesN) * BM;
  int colBase = (sw % nTilesN) * BN;

  const int t = threadIdx.x;
  const int lane = t & 63;
  const int wid = t >> 6;
  const int wr = wid >> 2, wc = wid & 3;   // 2M x 4N waves
  const int lr = lane & 15;
  const int lg = lane >> 4;                // 0..3
  const int r7 = lane & 7;

  // staging source (pre-swizzled global address, linear LDS dest)
  const int arow = t >> 3;                             // 0..63
  const int acolB = ((t & 7) * 16) ^ ((arow & 7) << 4);
  const unsigned short* aSrc = A  + (size_t)(rowBase + arow) * K + (acolB >> 1);
  const unsigned short* bSrc = Bt + (size_t)(colBase + arow) * K + (acolB >> 1);

  // swizzled ds_read bases (bytes); frag (i,ks): +i*2048, ^ (ks*64)
  const int aRd = (wr * WROWS + lr) * 128 + ((lg ^ r7) * 16);
  const int bRd = ABYTES + (wc * 64 + lr) * 128 + ((lg ^ r7) * 16);

  f32x4 acc[M_REP][4] = {};
  bf16x8 a[MH][2], b[4][2];

#define STAGE_A(T1, BO, j)                                                  \
  async16(aSrc + ((size_t)(j) * 64 * K + (size_t)(T1) * 64),                \
          &lds[(BO) + (j) * 8192 + t * 16])
#define STAGE_B(T2, BO, j)                                                  \
  async16(bSrc + ((size_t)(j) * 64 * K + (size_t)(T2) * 64),                \
          &lds[(BO) + ABYTES + (j) * 8192 + t * 16])

#define LDS_A(mh, BO)                                                       \
  _Pragma("unroll") for (int mi = 0; mi < MH; ++mi)                         \
  _Pragma("unroll") for (int ks = 0; ks < 2; ++ks)                          \
    a[mi][ks] = __builtin_bit_cast(bf16x8, *(const s16x8*)&lds[             \
        (BO) + ((aRd + ((mh) * MH + mi) * 2048) ^ (ks * 64))])
#define LDS_B(nh, BO)                                                       \
  _Pragma("unroll") for (int nn = 0; nn < 2; ++nn)                          \
  _Pragma("unroll") for (int ks = 0; ks < 2; ++ks)                          \
    b[(nh) * 2 + nn][ks] = __builtin_bit_cast(bf16x8, *(const s16x8*)&lds[  \
        (BO) + ((bRd + ((nh) * 2 + nn) * 2048) ^ (ks * 64))])

#define QUAD(mh, nh)                                                        \
  __builtin_amdgcn_s_setprio(1);                                            \
  _Pragma("unroll") for (int mi = 0; mi < MH; ++mi)                         \
  _Pragma("unroll") for (int nn = 0; nn < 2; ++nn)                          \
  _Pragma("unroll") for (int ks = 0; ks < 2; ++ks)                          \
    acc[(mh) * MH + mi][(nh) * 2 + nn] =                                    \
        __builtin_amdgcn_mfma_f32_16x16x32_bf16(                            \
            a[mi][ks], b[(nh) * 2 + nn][ks],                                \
            acc[(mh) * MH + mi][(nh) * 2 + nn], 0, 0, 0);                   \
  __builtin_amdgcn_s_setprio(0)

#define BAR() __builtin_amdgcn_s_barrier()
#define WAITLGKM()                                                          \
  asm volatile("s_waitcnt lgkmcnt(0)" ::: "memory");                        \
  __builtin_amdgcn_sched_barrier(0)

#define GROUP(T, BO, OBO) do {                                              \
    /* phase 1 */                                                           \
    LDS_A(0, BO); LDS_B(0, BO);                                             \
    if ((T) + 1 < NT) {                                                     \
      _Pragma("unroll") for (int j = 0; j < LA / 2; ++j)                    \
        STAGE_A((T) + 1, OBO, j);                                           \
    }                                                                       \
    BAR(); WAITLGKM();                                                      \
    QUAD(0, 0);                                                             \
    BAR();                                                                  \
    /* phase 2 */                                                           \
    LDS_B(1, BO);                                                           \
    if ((T) + 1 < NT) {                                                     \
      _Pragma("unroll") for (int j = LA / 2; j < LA; ++j)                   \
        STAGE_A((T) + 1, OBO, j);                                           \
    }                                                                       \
    BAR(); WAITLGKM();                                                      \
    QUAD(0, 1);                                                             \
    BAR();                                                                  \
    /* phase 3 */                                                           \
    LDS_A(1, BO);                                                           \
    if ((T) + 2 < NT) {                                                     \
      _Pragma("unroll") for (int j = 0; j < LB / 2; ++j)                    \
        STAGE_B((T) + 2, BO, j);                                            \
    }                                                                       \
    BAR(); WAITLGKM();                                                      \
    QUAD(1, 0);                                                             \
    BAR();                                                                  \
    /* phase 4 */                                                           \
    if ((T) + 2 < NT) {                                                     \
      _Pragma("unroll") for (int j = LB / 2; j < LB; ++j)                   \
        STAGE_B((T) + 2, BO, j);                                            \
    }                                                                       \
    BAR();                                                                  \
    QUAD(1, 1);                                                             \
    if ((T) < NT - 2) {                                                     \
      asm volatile("s_waitcnt vmcnt(4)" ::: "memory");                      \
    } else if ((T) == NT - 2) {                                             \
      asm volatile("s_waitcnt vmcnt(0)" ::: "memory");                      \
    }                                                                       \
    BAR();                                                                  \
  } while (0)

  // prologue: tile0 A+B, tile1 B; wait tile0 arrived (tile1 B may fly)
#pragma unroll
  for (int j = 0; j < LA; ++j) STAGE_A(0, 0, j);
#pragma unroll
  for (int j = 0; j < LB; ++j) STAGE_B(0, 0, j);
#pragma unroll
  for (int j = 0; j < LB; ++j) STAGE_B(1, BUF, j);
  asm volatile("s_waitcnt vmcnt(4)" ::: "memory");
  BAR();

  for (int T = 0; T < NT; T += 2) {
    GROUP(T, 0, BUF);
    GROUP(T + 1, BUF, 0);
  }

#undef GROUP
#undef QUAD
#undef LDS_A
#undef LDS_B
#undef STAGE_A
#undef STAGE_B
#undef BAR
#undef WAITLGKM

  // epilogue
  const int orow0 = rowBase + wr * WROWS + (lane >> 4) * 4;
  const int ocol0 = colBase + wc * 64 + lr;
#pragma unroll
  for (int ni = 0; ni < 4; ++ni) {
    int n = ocol0 + ni * 16;
    float bv = bias[n];
    float th = 0.f, cc = 0.f;
    if constexpr (FUSED) { th = theta[n]; cc = c1[n]; }
#pragma unroll
    for (int mi = 0; mi < M_REP; ++mi) {
#pragma unroll
      for (int r = 0; r < 4; ++r) {
        size_t m = (size_t)(orow0 + mi * 16 + r);
        float h = acc[mi][ni][r] + bv;
        if constexpr (FUSED) {
          float q = h + cc * __sinf(th + 0.1f * h);
          ((unsigned short*)Cout)[m * N + n] = f2bf(fmaxf(q, 0.f));
        } else {
          ((float*)Cout)[m * N + n] = h;
        }
      }
    }
  }
}

// ---------------- launch ----------------

extern "C" void kernel_launch(void* const* d_in, const int* in_sizes, int n_in,
                              void* d_out, int out_size, void* d_ws,
                              size_t ws_size, hipStream_t stream) {
  const float* x     = (const float*)d_in[0];
  const float* W1    = (const float*)d_in[1];
  const float* b1    = (const float*)d_in[2];
  const float* theta = (const float*)d_in[3];
  const float* qwr   = (const float*)d_in[4];
  const float* qwi   = (const float*)d_in[5];
  const float* W2    = (const float*)d_in[6];
  const float* b2    = (const float*)d_in[7];
  float* out = (float*)d_out;

  const int M = 4 * 2048;            // 8192
  const int DM = 1024, DF = 4096;

  size_t need = ((size_t)96 << 20) + DF * sizeof(float);
  if (ws_size < need) return;

  char* ws = (char*)d_ws;
  unsigned short* xb   = (unsigned short*)ws;                          // 16 MiB
  unsigned short* w1t  = (unsigned short*)(ws + ((size_t)16 << 20));   //  8 MiB
  unsigned short* w2t  = (unsigned short*)(ws + ((size_t)24 << 20));   //  8 MiB
  unsigned short* actb = (unsigned short*)(ws + ((size_t)32 << 20));   // 64 MiB
  float* c1 = (float*)(ws + ((size_t)96 << 20));

  cvt_f32_bf16<<<2048, 256, 0, stream>>>(x, xb, M * DM / 4);
  transpose_cvt<<<dim3(DF / 32, DM / 32), 256, 0, stream>>>(W1, w1t, DM, DF);
  transpose_cvt<<<dim3(DM / 32, DF / 32), 256, 0, stream>>>(W2, w2t, DF, DM);
  qconst<<<DF / 256, 256, 0, stream>>>(theta, qwr, qwi, c1, DF);

  // GEMM1: 8192x4096, K=1024 -> 32x16 = 512 blocks (256x256 tile)
  gemm8p<256, 256, 16, true><<<512, 512, 0, stream>>>(
      xb, w1t, b1, theta, c1, (void*)actb, DF, DF / 256);
  // GEMM2: 8192x1024, K=4096 -> 64x4 = 256 blocks (128x256 tile)
  gemm8p<128, 256, 64, false><<<256, 512, 0, stream>>>(
      actb, w2t, b2, nullptr, nullptr, (void*)out, DM, DM / 256);
}

// Round 4
// 159.783 us; speedup vs baseline: 9.2797x; 1.0352x over previous
//
#include <hip/hip_runtime.h>

typedef __bf16 bf16x8 __attribute__((ext_vector_type(8)));
typedef short  s16x8  __attribute__((ext_vector_type(8)));
typedef float  f32x4  __attribute__((ext_vector_type(4)));

#define DEVINL __device__ __forceinline__

DEVINL unsigned short f2bf(float f) {
  unsigned int u = __builtin_bit_cast(unsigned int, f);
  u += 0x7fffu + ((u >> 16) & 1u);   // round-to-nearest-even
  return (unsigned short)(u >> 16);
}

DEVINL void async16(const void* g, void* l) {
  __builtin_amdgcn_global_load_lds(
      (const __attribute__((address_space(1))) unsigned int*)g,
      (__attribute__((address_space(3))) unsigned int*)l, 16, 0, 0);
}

// ---------------- conversion kernels ----------------

__global__ void cvt_f32_bf16(const float* __restrict__ in,
                             unsigned short* __restrict__ out, int n4) {
  int i = blockIdx.x * blockDim.x + threadIdx.x;
  int stride = gridDim.x * blockDim.x;
  for (; i < n4; i += stride) {
    float4 v = ((const float4*)in)[i];
    ushort4 o;
    o.x = f2bf(v.x); o.y = f2bf(v.y); o.z = f2bf(v.z); o.w = f2bf(v.w);
    ((ushort4*)out)[i] = o;
  }
}

// in: [R][C] fp32  ->  out: [C][R] bf16
__global__ void transpose_cvt(const float* __restrict__ in,
                              unsigned short* __restrict__ out, int R, int C) {
  __shared__ unsigned short tile[32][33];
  int bc = blockIdx.x * 32, br = blockIdx.y * 32;
  int tx = threadIdx.x & 31, ty = threadIdx.x >> 5;
#pragma unroll
  for (int i = 0; i < 32; i += 8)
    tile[ty + i][tx] = f2bf(in[(size_t)(br + ty + i) * C + (bc + tx)]);
  __syncthreads();
#pragma unroll
  for (int i = 0; i < 32; i += 8)
    out[(size_t)(bc + ty + i) * R + (br + tx)] = tile[tx][ty + i];
}

__global__ void qconst(const float* __restrict__ theta,
                       const float* __restrict__ wre,
                       const float* __restrict__ wim,
                       float* __restrict__ c1, int n) {
  int i = blockIdx.x * blockDim.x + threadIdx.x;
  if (i < n) {
    float t = theta[i];
    c1[i] = (cosf(t) * wre[i] + sinf(t) * wim[i]) * wim[i] * 0.1f;
  }
}

// ---------------- 8-phase GEMM: C = A[M][K] * Bt[N][K]^T ----------------
// BMxBN tile, BK=64, 8 waves (2M x 4N), double-buffered LDS, counted vmcnt,
// XOR-swizzled LDS (pre-swizzled global source + swizzled ds_read).
// Sync structure (2 barriers per K-tile, compiler-managed lgkm waits):
//   half1: read A0,B0,B1; stage A(T+1)->buf^1; QUAD(0,0),(0,1);
//          lgkmcnt(0); barrier        <- all reads of B-region complete
//   half2: read A1; stage B(T+2)->buf; QUAD(1,0),(1,1);
//          lgkmcnt(0); vmcnt(4); barrier
// Hazards: B-region overwrite (stage B(T+2), half2) is issued only after the
//   mid barrier, which every wave reaches only after lgkmcnt(0) completes its
//   B-reads. A-region overwrite (stage A(T+2), next group half1) is after the
//   group-end drain+barrier. Tile T+1 arrival: steady-state outstanding queue
//   at the vmcnt point = [B(T+1)x4, A(T+1)x4, B(T+2)x4]; vmcnt(4) drains
//   exactly tile T+1; the end barrier publishes it to all waves.

template <int BM, int BN, int NT, bool FUSED>
__global__ __launch_bounds__(512, 2) void gemm8p(
    const unsigned short* __restrict__ A,
    const unsigned short* __restrict__ Bt,
    const float* __restrict__ bias,
    const float* __restrict__ theta,
    const float* __restrict__ c1,
    void* __restrict__ Cout,
    int N, int nTilesN) {
  constexpr int K      = NT * 64;
  constexpr int WROWS  = BM / 2;        // per-wave output rows
  constexpr int M_REP  = WROWS / 16;    // 8 (BM=256) or 4 (BM=128)
  constexpr int MH     = M_REP / 2;
  constexpr int ABYTES = BM * 128;      // A region bytes per buffer
  constexpr int BUF    = (BM + BN) * 128;
  constexpr int LA     = ABYTES / 8192; // per-thread A loads per K-tile (4 or 2)
  constexpr int LB     = BN * 128 / 8192;
  static_assert(LB == 4 && (LA == 4 || LA == 2), "geometry");

  __shared__ __align__(16) char lds[2 * BUF];

  // bijective XCD swizzle (grid % 8 == 0 for both instantiations)
  int nwg = gridDim.x;
  int wg = blockIdx.x;
  int sw = (wg & 7) * (nwg >> 3) + (wg >> 3);
  int rowBase = (sw / nTilesN) * BM;
  int colBase = (sw % nTilesN) * BN;

  const int t = threadIdx.x;
  const int lane = t & 63;
  const int wid = t >> 6;
  const int wr = wid >> 2, wc = wid & 3;   // 2M x 4N waves
  const int lr = lane & 15;
  const int lg = lane >> 4;                // 0..3
  const int r7 = lane & 7;

  // staging source (pre-swizzled global address, linear LDS dest)
  const int arow = t >> 3;                             // 0..63
  const int acolB = ((t & 7) * 16) ^ ((arow & 7) << 4);
  const unsigned short* aSrc = A  + (size_t)(rowBase + arow) * K + (acolB >> 1);
  const unsigned short* bSrc = Bt + (size_t)(colBase + arow) * K + (acolB >> 1);

  // swizzled ds_read bases (bytes); frag (i,ks): +i*2048, ^ (ks*64)
  const int aRd = (wr * WROWS + lr) * 128 + ((lg ^ r7) * 16);
  const int bRd = ABYTES + (wc * 64 + lr) * 128 + ((lg ^ r7) * 16);

  f32x4 acc[M_REP][4] = {};
  bf16x8 a[MH][2], b[4][2];

#define STAGE_A(T1, BO, j)                                                  \
  async16(aSrc + ((size_t)(j) * 64 * K + (size_t)(T1) * 64),                \
          &lds[(BO) + (j) * 8192 + t * 16])
#define STAGE_B(T2, BO, j)                                                  \
  async16(bSrc + ((size_t)(j) * 64 * K + (size_t)(T2) * 64),                \
          &lds[(BO) + ABYTES + (j) * 8192 + t * 16])

#define LDS_A(mh, BO)                                                       \
  _Pragma("unroll") for (int mi = 0; mi < MH; ++mi)                         \
  _Pragma("unroll") for (int ks = 0; ks < 2; ++ks)                          \
    a[mi][ks] = __builtin_bit_cast(bf16x8, *(const s16x8*)&lds[             \
        (BO) + ((aRd + ((mh) * MH + mi) * 2048) ^ (ks * 64))])
#define LDS_B(nh, BO)                                                       \
  _Pragma("unroll") for (int nn = 0; nn < 2; ++nn)                          \
  _Pragma("unroll") for (int ks = 0; ks < 2; ++ks)                          \
    b[(nh) * 2 + nn][ks] = __builtin_bit_cast(bf16x8, *(const s16x8*)&lds[  \
        (BO) + ((bRd + ((nh) * 2 + nn) * 2048) ^ (ks * 64))])

#define QUAD(mh, nh)                                                        \
  __builtin_amdgcn_s_setprio(1);                                            \
  _Pragma("unroll") for (int mi = 0; mi < MH; ++mi)                         \
  _Pragma("unroll") for (int nn = 0; nn < 2; ++nn)                          \
  _Pragma("unroll") for (int ks = 0; ks < 2; ++ks)                          \
    acc[(mh) * MH + mi][(nh) * 2 + nn] =                                    \
        __builtin_amdgcn_mfma_f32_16x16x32_bf16(                            \
            a[mi][ks], b[(nh) * 2 + nn][ks],                                \
            acc[(mh) * MH + mi][(nh) * 2 + nn], 0, 0, 0);                   \
  __builtin_amdgcn_s_setprio(0)

#define BAR() __builtin_amdgcn_s_barrier()
#define DRAIN_LGKM() asm volatile("s_waitcnt lgkmcnt(0)" ::: "memory")

#define GROUP(T, BO, OBO) do {                                              \
    /* half 1 */                                                            \
    LDS_A(0, BO); LDS_B(0, BO);                                             \
    if ((T) + 1 < NT) {                                                     \
      _Pragma("unroll") for (int j = 0; j < LA; ++j)                        \
        STAGE_A((T) + 1, OBO, j);                                           \
    }                                                                       \
    QUAD(0, 0);                                                             \
    LDS_B(1, BO);                                                           \
    QUAD(0, 1);                                                             \
    DRAIN_LGKM();                                                           \
    BAR();                                                                  \
    /* half 2 */                                                            \
    LDS_A(1, BO);                                                           \
    if ((T) + 2 < NT) {                                                     \
      _Pragma("unroll") for (int j = 0; j < LB; ++j)                        \
        STAGE_B((T) + 2, BO, j);                                            \
    }                                                                       \
    QUAD(1, 0);                                                             \
    QUAD(1, 1);                                                             \
    DRAIN_LGKM();                                                           \
    if ((T) < NT - 2) {                                                     \
      asm volatile("s_waitcnt vmcnt(4)" ::: "memory");                      \
    } else if ((T) == NT - 2) {                                             \
      asm volatile("s_waitcnt vmcnt(0)" ::: "memory");                      \
    }                                                                       \
    BAR();                                                                  \
  } while (0)

  // prologue: tile0 A+B, tile1 B; wait tile0 arrived (tile1 B may fly)
#pragma unroll
  for (int j = 0; j < LA; ++j) STAGE_A(0, 0, j);
#pragma unroll
  for (int j = 0; j < LB; ++j) STAGE_B(0, 0, j);
#pragma unroll
  for (int j = 0; j < LB; ++j) STAGE_B(1, BUF, j);
  asm volatile("s_waitcnt vmcnt(4)" ::: "memory");
  BAR();

  for (int T = 0; T < NT; T += 2) {
    GROUP(T, 0, BUF);
    GROUP(T + 1, BUF, 0);
  }

#undef GROUP
#undef QUAD
#undef LDS_A
#undef LDS_B
#undef STAGE_A
#undef STAGE_B
#undef BAR
#undef DRAIN_LGKM

  // epilogue
  const int orow0 = rowBase + wr * WROWS + (lane >> 4) * 4;
  const int ocol0 = colBase + wc * 64 + lr;
#pragma unroll
  for (int ni = 0; ni < 4; ++ni) {
    int n = ocol0 + ni * 16;
    float bv = bias[n];
    float th = 0.f, cc = 0.f;
    if constexpr (FUSED) { th = theta[n]; cc = c1[n]; }
#pragma unroll
    for (int mi = 0; mi < M_REP; ++mi) {
#pragma unroll
      for (int r = 0; r < 4; ++r) {
        size_t m = (size_t)(orow0 + mi * 16 + r);
        float h = acc[mi][ni][r] + bv;
        if constexpr (FUSED) {
          float q = h + cc * __sinf(th + 0.1f * h);
          ((unsigned short*)Cout)[m * N + n] = f2bf(fmaxf(q, 0.f));
        } else {
          ((float*)Cout)[m * N + n] = h;
        }
      }
    }
  }
}

// ---------------- launch ----------------

extern "C" void kernel_launch(void* const* d_in, const int* in_sizes, int n_in,
                              void* d_out, int out_size, void* d_ws,
                              size_t ws_size, hipStream_t stream) {
  const float* x     = (const float*)d_in[0];
  const float* W1    = (const float*)d_in[1];
  const float* b1    = (const float*)d_in[2];
  const float* theta = (const float*)d_in[3];
  const float* qwr   = (const float*)d_in[4];
  const float* qwi   = (const float*)d_in[5];
  const float* W2    = (const float*)d_in[6];
  const float* b2    = (const float*)d_in[7];
  float* out = (float*)d_out;

  const int M = 4 * 2048;            // 8192
  const int DM = 1024, DF = 4096;

  size_t need = ((size_t)96 << 20) + DF * sizeof(float);
  if (ws_size < need) return;

  char* ws = (char*)d_ws;
  unsigned short* xb   = (unsigned short*)ws;                          // 16 MiB
  unsigned short* w1t  = (unsigned short*)(ws + ((size_t)16 << 20));   //  8 MiB
  unsigned short* w2t  = (unsigned short*)(ws + ((size_t)24 << 20));   //  8 MiB
  unsigned short* actb = (unsigned short*)(ws + ((size_t)32 << 20));   // 64 MiB
  float* c1 = (float*)(ws + ((size_t)96 << 20));

  cvt_f32_bf16<<<2048, 256, 0, stream>>>(x, xb, M * DM / 4);
  transpose_cvt<<<dim3(DF / 32, DM / 32), 256, 0, stream>>>(W1, w1t, DM, DF);
  transpose_cvt<<<dim3(DM / 32, DF / 32), 256, 0, stream>>>(W2, w2t, DF, DM);
  qconst<<<DF / 256, 256, 0, stream>>>(theta, qwr, qwi, c1, DF);

  // GEMM1: 8192x4096, K=1024 -> 32x16 = 512 blocks (256x256 tile)
  gemm8p<256, 256, 16, true><<<512, 512, 0, stream>>>(
      xb, w1t, b1, theta, c1, (void*)actb, DF, DF / 256);
  // GEMM2: 8192x1024, K=4096 -> 64x4 = 256 blocks (128x256 tile)
  gemm8p<128, 256, 64, false><<<256, 512, 0, stream>>>(
      actb, w2t, b2, nullptr, nullptr, (void*)out, DM, DM / 256);
}